// Round 1
// baseline (250.554 us; speedup 1.0000x reference)
//
#include <hip/hip_runtime.h>

#define F  10
#define HU 64
#define HP 64
#define NP 9   // pair count = F-1

// Branchless Abramowitz-Stegun 7.1.26 erf, abs err ~1e-6 in f32.
__device__ __forceinline__ float fast_erf(float v) {
    float ax = fabsf(v);
    float t  = __builtin_amdgcn_rcpf(fmaf(0.3275911f, ax, 1.0f));
    float p  = fmaf(1.061405429f, t, -1.453152027f);
    p = fmaf(p, t, 1.421413741f);
    p = fmaf(p, t, -0.284496736f);
    p = fmaf(p, t, 0.254829592f);
    p = p * t;
    float e = __expf(-ax * ax);
    float r = fmaf(-p, e, 1.0f);   // 1 - p*e
    return copysignf(r, v);
}

__device__ __forceinline__ float gelu_exact(float v) {
    return 0.5f * v * (1.0f + fast_erf(v * 0.70710678118654752f));
}

__global__ __launch_bounds__(256) void siarm_kernel(
    const float* __restrict__ x,
    const float* __restrict__ rmean,
    const float* __restrict__ rstd,
    const float* __restrict__ w1f,
    const float* __restrict__ b1f,
    const float* __restrict__ w2f,
    const float* __restrict__ b2f,
    const float* __restrict__ w1p,   // [P][2][HP]
    const float* __restrict__ b1p,   // [P][HP]
    const float* __restrict__ w2p,   // [P][HP]
    const float* __restrict__ b2p,   // [P]
    const int*  __restrict__ crpp,
    float* __restrict__ out,
    int nrows)
{
    int r = blockIdx.x * 256 + threadIdx.x;
    if (r >= nrows) return;
    const int crp = crpp[0];
    const size_t base = (size_t)r * F;

    // ---- z0 (age) ----
    float raw0 = x[base + 0];
    if (crp == 0) raw0 = __logf(fmaxf(raw0 * 10.0f, 1e-6f));
    const float z0 = (raw0 - rmean[0]) / rstd[0];

    // ---- additive net for feature 0 ----
    float acc = b2f[0];
    {
        float s = 0.0f;
        #pragma unroll 8
        for (int h = 0; h < HU; ++h) {
            float t = fmaf(z0, w1f[h], b1f[h]);
            s = fmaf(gelu_exact(t), w2f[h], s);
        }
        acc += s;
    }

    // ---- features 1..9: additive net + pair net (share z[f]) ----
    #pragma unroll 1
    for (int f = 1; f < F; ++f) {
        float raw = x[base + f];
        if (f == crp) raw = __logf(fmaxf(raw * 10.0f, 1e-6f));
        const float zf = (raw - rmean[f]) / rstd[f];

        float sa = 0.0f;
        #pragma unroll 8
        for (int h = 0; h < HU; ++h) {
            float t = fmaf(zf, w1f[f * HU + h], b1f[f * HU + h]);
            sa = fmaf(gelu_exact(t), w2f[f * HU + h], sa);
        }

        const int p = f - 1;
        float sp = 0.0f;
        #pragma unroll 8
        for (int h = 0; h < HP; ++h) {
            float t = fmaf(z0, w1p[(2 * p) * HP + h],
                      fmaf(zf, w1p[(2 * p + 1) * HP + h], b1p[p * HP + h]));
            sp = fmaf(gelu_exact(t), w2p[p * HP + h], sp);
        }

        acc += sa + b2f[f] + sp + b2p[p];
    }

    out[r] = acc;
}

extern "C" void kernel_launch(void* const* d_in, const int* in_sizes, int n_in,
                              void* d_out, int out_size, void* d_ws, size_t ws_size,
                              hipStream_t stream) {
    const float* x     = (const float*)d_in[0];
    const float* rmean = (const float*)d_in[1];
    const float* rstd  = (const float*)d_in[2];
    const float* w1f   = (const float*)d_in[3];
    const float* b1f   = (const float*)d_in[4];
    const float* w2f   = (const float*)d_in[5];
    const float* b2f   = (const float*)d_in[6];
    const float* w1p   = (const float*)d_in[7];
    const float* b1p   = (const float*)d_in[8];
    const float* w2p   = (const float*)d_in[9];
    const float* b2p   = (const float*)d_in[10];
    const int*   crp   = (const int*)d_in[11];
    float* out = (float*)d_out;

    int nrows = out_size;                 // [B] output
    int grid  = (nrows + 255) / 256;
    hipLaunchKernelGGL(siarm_kernel, dim3(grid), dim3(256), 0, stream,
                       x, rmean, rstd, w1f, b1f, w2f, b2f,
                       w1p, b1p, w2p, b2p, crp, out, nrows);
}

// Round 2
// 117.999 us; speedup vs baseline: 2.1234x; 2.1234x over previous
//
#include <hip/hip_runtime.h>

#define NF 10
#define NH 64
#define NP 9

#define FT_N 4096            // 1-D table entries per feature
#define PT_N 256             // 2-D table entries per axis
#define TLO (-16.0f)
#define THI (6.0f)

// Branchless Abramowitz-Stegun 7.1.26 erf, abs err ~1e-6 in f32.
__device__ __forceinline__ float fast_erf(float v) {
    float ax = fabsf(v);
    float t  = __builtin_amdgcn_rcpf(fmaf(0.3275911f, ax, 1.0f));
    float p  = fmaf(1.061405429f, t, -1.453152027f);
    p = fmaf(p, t, 1.421413741f);
    p = fmaf(p, t, -0.284496736f);
    p = fmaf(p, t, 0.254829592f);
    p = p * t;
    float e = __expf(-ax * ax);
    float r = fmaf(-p, e, 1.0f);   // 1 - p*e
    return copysignf(r, v);
}

__device__ __forceinline__ float gelu_exact(float v) {
    return 0.5f * v * (1.0f + fast_erf(v * 0.70710678118654752f));
}

// ---- build 1-D feature tables: ftab[f][i] = b2f[f] + sum_h w2f[f,h]*gelu(z_i*w1f[f,h]+b1f[f,h])
__global__ __launch_bounds__(256) void build_ftab(
    const float* __restrict__ w1f, const float* __restrict__ b1f,
    const float* __restrict__ w2f, const float* __restrict__ b2f,
    float* __restrict__ ftab)
{
    int tid = blockIdx.x * 256 + threadIdx.x;      // NF*FT_N threads
    int f = tid >> 12;                             // FT_N = 4096
    int i = tid & (FT_N - 1);
    const float dz = (THI - TLO) / (float)(FT_N - 1);
    float z = TLO + dz * (float)i;
    float s = b2f[f];
    #pragma unroll 8
    for (int h = 0; h < NH; ++h) {
        float t = fmaf(z, w1f[f * NH + h], b1f[f * NH + h]);
        s = fmaf(gelu_exact(t), w2f[f * NH + h], s);
    }
    ftab[tid] = s;
}

// ---- build 2-D pair tables: ptab[p][i0][j] = b2p[p] + sum_h w2p*gelu(z0*a + zf*b + c)
__global__ __launch_bounds__(256) void build_ptab(
    const float* __restrict__ w1p, const float* __restrict__ b1p,
    const float* __restrict__ w2p, const float* __restrict__ b2p,
    float* __restrict__ ptab)
{
    int p  = blockIdx.x >> 8;        // NP * PT_N blocks of PT_N threads
    int i0 = blockIdx.x & (PT_N - 1);
    int j  = threadIdx.x;
    const float dz = (THI - TLO) / (float)(PT_N - 1);
    float z0 = TLO + dz * (float)i0;   // wave-uniform
    float zf = TLO + dz * (float)j;    // per-lane
    float s = b2p[p];
    #pragma unroll 8
    for (int h = 0; h < NH; ++h) {
        float a = w1p[(2 * p + 0) * NH + h];
        float b = w1p[(2 * p + 1) * NH + h];
        float t = fmaf(z0, a, fmaf(zf, b, b1p[p * NH + h]));
        s = fmaf(gelu_exact(t), w2p[p * NH + h], s);
    }
    ptab[(p * PT_N + i0) * PT_N + j] = s;
}

// ---- main: per-row table lookups
__global__ __launch_bounds__(256) void siarm_main(
    const float* __restrict__ x,
    const float* __restrict__ rmean, const float* __restrict__ rstd,
    const int*  __restrict__ crpp,
    const float* __restrict__ ftab, const float* __restrict__ ptab,
    float* __restrict__ out, int nrows)
{
    int r = blockIdx.x * 256 + threadIdx.x;
    if (r >= nrows) return;
    const int crp = crpp[0];

    const float2* xr = reinterpret_cast<const float2*>(x + (size_t)r * NF);
    float raw[NF];
    #pragma unroll
    for (int q = 0; q < NF / 2; ++q) {
        float2 v = xr[q];
        raw[2 * q] = v.x; raw[2 * q + 1] = v.y;
    }

    float z[NF];
    #pragma unroll
    for (int f = 0; f < NF; ++f) {
        float rv = raw[f];
        if (f == crp) rv = __logf(fmaxf(rv * 10.0f, 1e-6f));
        z[f] = (rv - rmean[f]) * __builtin_amdgcn_rcpf(rstd[f]);
    }

    float acc = 0.0f;

    // additive 1-D lookups
    const float invf = (float)(FT_N - 1) / (THI - TLO);
    #pragma unroll
    for (int f = 0; f < NF; ++f) {
        float c = fminf(fmaxf((z[f] - TLO) * invf, 0.0f), (float)(FT_N - 2));
        float fi = floorf(c);
        float fr = c - fi;
        int i = (int)fi;
        const float* tf = ftab + f * FT_N + i;
        float lo = tf[0], hi = tf[1];
        acc += fmaf(fr, hi - lo, lo);
    }

    // pairwise 2-D bilinear lookups (z0 index shared)
    const float invp = (float)(PT_N - 1) / (THI - TLO);
    float c0 = fminf(fmaxf((z[0] - TLO) * invp, 0.0f), (float)(PT_N - 2));
    float f0 = floorf(c0);
    float fr0 = c0 - f0;
    int i0 = (int)f0;
    #pragma unroll
    for (int p = 0; p < NP; ++p) {
        float cf = fminf(fmaxf((z[p + 1] - TLO) * invp, 0.0f), (float)(PT_N - 2));
        float ff = floorf(cf);
        float frf = cf - ff;
        int jf = (int)ff;
        const float* tp = ptab + ((size_t)(p * PT_N + i0) * PT_N + jf);
        float v00 = tp[0],     v01 = tp[1];
        float v10 = tp[PT_N],  v11 = tp[PT_N + 1];
        float lo = fmaf(frf, v01 - v00, v00);
        float hi = fmaf(frf, v11 - v10, v10);
        acc += fmaf(fr0, hi - lo, lo);
    }

    out[r] = acc;
}

// ---- fallback: direct compute (round-1 kernel), used only if ws too small
__global__ __launch_bounds__(256) void siarm_direct(
    const float* __restrict__ x,
    const float* __restrict__ rmean, const float* __restrict__ rstd,
    const float* __restrict__ w1f, const float* __restrict__ b1f,
    const float* __restrict__ w2f, const float* __restrict__ b2f,
    const float* __restrict__ w1p, const float* __restrict__ b1p,
    const float* __restrict__ w2p, const float* __restrict__ b2p,
    const int*  __restrict__ crpp,
    float* __restrict__ out, int nrows)
{
    int r = blockIdx.x * 256 + threadIdx.x;
    if (r >= nrows) return;
    const int crp = crpp[0];
    const size_t base = (size_t)r * NF;

    float raw0 = x[base + 0];
    if (crp == 0) raw0 = __logf(fmaxf(raw0 * 10.0f, 1e-6f));
    const float z0 = (raw0 - rmean[0]) / rstd[0];

    float acc = b2f[0];
    {
        float s = 0.0f;
        #pragma unroll 8
        for (int h = 0; h < NH; ++h) {
            float t = fmaf(z0, w1f[h], b1f[h]);
            s = fmaf(gelu_exact(t), w2f[h], s);
        }
        acc += s;
    }
    #pragma unroll 1
    for (int f = 1; f < NF; ++f) {
        float raw = x[base + f];
        if (f == crp) raw = __logf(fmaxf(raw * 10.0f, 1e-6f));
        const float zf = (raw - rmean[f]) / rstd[f];

        float sa = 0.0f;
        #pragma unroll 8
        for (int h = 0; h < NH; ++h) {
            float t = fmaf(zf, w1f[f * NH + h], b1f[f * NH + h]);
            sa = fmaf(gelu_exact(t), w2f[f * NH + h], sa);
        }
        const int p = f - 1;
        float sp = 0.0f;
        #pragma unroll 8
        for (int h = 0; h < NH; ++h) {
            float t = fmaf(z0, w1p[(2 * p) * NH + h],
                      fmaf(zf, w1p[(2 * p + 1) * NH + h], b1p[p * NH + h]));
            sp = fmaf(gelu_exact(t), w2p[p * NH + h], sp);
        }
        acc += sa + b2f[f] + sp + b2p[p];
    }
    out[r] = acc;
}

extern "C" void kernel_launch(void* const* d_in, const int* in_sizes, int n_in,
                              void* d_out, int out_size, void* d_ws, size_t ws_size,
                              hipStream_t stream) {
    const float* x     = (const float*)d_in[0];
    const float* rmean = (const float*)d_in[1];
    const float* rstd  = (const float*)d_in[2];
    const float* w1f   = (const float*)d_in[3];
    const float* b1f   = (const float*)d_in[4];
    const float* w2f   = (const float*)d_in[5];
    const float* b2f   = (const float*)d_in[6];
    const float* w1p   = (const float*)d_in[7];
    const float* b1p   = (const float*)d_in[8];
    const float* w2p   = (const float*)d_in[9];
    const float* b2p   = (const float*)d_in[10];
    const int*   crp   = (const int*)d_in[11];
    float* out = (float*)d_out;

    int nrows = out_size;
    const size_t ftab_sz = (size_t)NF * FT_N * sizeof(float);        // 160 KB
    const size_t ptab_sz = (size_t)NP * PT_N * PT_N * sizeof(float); // 2.25 MB

    if (ws_size >= ftab_sz + ptab_sz) {
        float* ftab = (float*)d_ws;
        float* ptab = (float*)((char*)d_ws + ftab_sz);
        hipLaunchKernelGGL(build_ftab, dim3(NF * FT_N / 256), dim3(256), 0, stream,
                           w1f, b1f, w2f, b2f, ftab);
        hipLaunchKernelGGL(build_ptab, dim3(NP * PT_N), dim3(256), 0, stream,
                           w1p, b1p, w2p, b2p, ptab);
        hipLaunchKernelGGL(siarm_main, dim3((nrows + 255) / 256), dim3(256), 0, stream,
                           x, rmean, rstd, crp, ftab, ptab, out, nrows);
    } else {
        hipLaunchKernelGGL(siarm_direct, dim3((nrows + 255) / 256), dim3(256), 0, stream,
                           x, rmean, rstd, w1f, b1f, w2f, b2f,
                           w1p, b1p, w2p, b2p, crp, out, nrows);
    }
}